// Round 22
// baseline (133.214 us; speedup 1.0000x reference)
//
#include <hip/hip_runtime.h>

#define NN 50000
#define NE 800000
#define NF 128
#define DIM 32
#define NG 500
#define BK 32                         // nodes per bucket
#define NB ((NN + BK - 1) / BK)       // 1563 buckets
#define PB 782                        // proj blocks (64 rows each)
#define HB 128                        // histogram/partition blocks
#define CHUNK_E ((NE + HB - 1) / HB)  // 6250 edges per block
#define CAP 1024                      // LDS csr capacity (mean 512, +22sigma)
#define SC7 7                         // scan elements per thread (256*7 >= NB+1)

typedef float  f32x4  __attribute__((ext_vector_type(4)));
typedef __bf16 bf16x8 __attribute__((ext_vector_type(8)));
typedef unsigned short u16x8 __attribute__((ext_vector_type(8)));

__device__ __forceinline__ unsigned rne16(float f) {
    unsigned u = __float_as_uint(f);
    return (u + 0x7FFFu + ((u >> 16) & 1u)) >> 16;   // bf16 round-to-nearest-even
}
#define UIF __uint_as_float
__device__ __forceinline__ float blo(unsigned p) { return UIF(p << 16); }
__device__ __forceinline__ float bhi(unsigned p) { return UIF(p & 0xFFFF0000u); }

// ---------- k1: [blocks 0..PB-1] MFMA proj ; [blocks PB..] histk + zero pooled ----------
__global__ __launch_bounds__(256) void projhist_kernel(
    const float* __restrict__ x, const float* __restrict__ w_rel,
    const float* __restrict__ w_root, const float* __restrict__ b_rel,
    unsigned* __restrict__ yp, unsigned* __restrict__ rootp,
    const int* __restrict__ ei, int* __restrict__ H, float* __restrict__ pooled)
{
    __shared__ unsigned short s_wb[64 * 136];   // 17.4 KB: W^T bf16, padded
    __shared__ float s_out[64 * 65];            // 16.6 KB: D staging, padded
    int tid = threadIdx.x;

    if (blockIdx.x >= PB) {
        // ---- histk branch (reuses s_wb as int[]) ----
        int blk = blockIdx.x - PB;
        int row = ((blk & 7) << 4) | (blk >> 3);   // XCD-aware: same-XCD rows adjacent
        int* sh = (int*)s_wb;
        int pi = blk * 256 + tid;
        if (pi < NG * DIM) pooled[pi] = 0.0f;
        for (int i = tid; i < NB; i += 256) sh[i] = 0;
        __syncthreads();
        int base = row * CHUNK_E;
        int end  = min(base + CHUNK_E, NE);
        for (int e = base + tid; e < end; e += 256)
            atomicAdd(&sh[ei[NE + e] >> 5], 1);
        __syncthreads();
        for (int i = tid; i < NB; i += 256) H[row * NB + i] = sh[i];
        return;
    }

    // ---- stage W = [w_rel | w_root] transposed to LDS as bf16 ----
    for (int i = tid; i < 64 * NF; i += 256) {
        int k   = i >> 6;          // 0..127
        int col = i & 63;          // 0..63
        float v = (col < DIM) ? w_rel[k * DIM + col] : w_root[k * DIM + (col - DIM)];
        s_wb[col * 136 + k] = (unsigned short)rne16(v);
    }
    int rb = blockIdx.x * 64;
    __syncthreads();

    // ---- MFMA: wave w computes rows rb+w*16..+15 x 64 cols ----
    int l    = tid & 63;
    int w    = tid >> 6;
    int mrow = l & 15;
    int q    = l >> 4;                 // k-quad for A/B, row-quad for D
    int arow = min(rb + w * 16 + mrow, NN - 1);
    const float* xr = x + (size_t)arow * NF + q * 8;

    f32x4 acc0 = {0,0,0,0}, acc1 = {0,0,0,0}, acc2 = {0,0,0,0}, acc3 = {0,0,0,0};
#pragma unroll
    for (int k0 = 0; k0 < NF; k0 += 32) {
        float4 xa = *reinterpret_cast<const float4*>(xr + k0);
        float4 xb = *reinterpret_cast<const float4*>(xr + k0 + 4);
        u16x8 au;
        au[0] = (unsigned short)rne16(xa.x); au[1] = (unsigned short)rne16(xa.y);
        au[2] = (unsigned short)rne16(xa.z); au[3] = (unsigned short)rne16(xa.w);
        au[4] = (unsigned short)rne16(xb.x); au[5] = (unsigned short)rne16(xb.y);
        au[6] = (unsigned short)rne16(xb.z); au[7] = (unsigned short)rne16(xb.w);
        bf16x8 a = __builtin_bit_cast(bf16x8, au);
        int kb = k0 + q * 8;
        bf16x8 b0 = *reinterpret_cast<const bf16x8*>(&s_wb[(0  + mrow) * 136 + kb]);
        bf16x8 b1 = *reinterpret_cast<const bf16x8*>(&s_wb[(16 + mrow) * 136 + kb]);
        bf16x8 b2 = *reinterpret_cast<const bf16x8*>(&s_wb[(32 + mrow) * 136 + kb]);
        bf16x8 b3 = *reinterpret_cast<const bf16x8*>(&s_wb[(48 + mrow) * 136 + kb]);
        acc0 = __builtin_amdgcn_mfma_f32_16x16x32_bf16(a, b0, acc0, 0, 0, 0);
        acc1 = __builtin_amdgcn_mfma_f32_16x16x32_bf16(a, b1, acc1, 0, 0, 0);
        acc2 = __builtin_amdgcn_mfma_f32_16x16x32_bf16(a, b2, acc2, 0, 0, 0);
        acc3 = __builtin_amdgcn_mfma_f32_16x16x32_bf16(a, b3, acc3, 0, 0, 0);
    }
    // D layout: col = lane&15, row = (lane>>4)*4 + reg  [m89-verified]
#pragma unroll
    for (int reg = 0; reg < 4; ++reg) {
        int srow = w * 16 + q * 4 + reg;
        s_out[srow * 65 +  0 + mrow] = acc0[reg];
        s_out[srow * 65 + 16 + mrow] = acc1[reg];
        s_out[srow * 65 + 32 + mrow] = acc2[reg];
        s_out[srow * 65 + 48 + mrow] = acc3[reg];
    }
    __syncthreads();

    // ---- repack + store: cols 0..31 -> yp ; cols 32..63 + b_rel -> rootp ----
#pragma unroll
    for (int rep = 0; rep < 8; ++rep) {
        int idx = tid + rep * 256;     // 0..2047
        int row = idx >> 5;            // 0..63
        int ui  = idx & 31;            // packed-uint index
        int n   = rb + row;
        if (n < NN) {
            if (ui < 16) {
                int c0 = ui * 2;
                unsigned p = rne16(s_out[row * 65 + c0]) |
                             (rne16(s_out[row * 65 + c0 + 1]) << 16);
                yp[(size_t)n * 16 + ui] = p;
            } else {
                int c0 = (ui - 16) * 2;
                float f0 = s_out[row * 65 + DIM + c0]     + b_rel[c0];
                float f1 = s_out[row * 65 + DIM + c0 + 1] + b_rel[c0 + 1];
                rootp[(size_t)n * 16 + (ui - 16)] = rne16(f0) | (rne16(f1) << 16);
            }
        }
    }
}

// ---------- k2: column prefix over the HB block rows -> colsum ----------
__global__ __launch_bounds__(256) void colscan(
    int* __restrict__ H, int* __restrict__ colsum)
{
    int b = blockIdx.x * 256 + threadIdx.x;
    if (b >= NB) return;
    int run = 0;
#pragma unroll 8
    for (int blk = 0; blk < HB; ++blk) {
        int v = H[blk * NB + b];   // coalesced across threads
        H[blk * NB + b] = run;
        run += v;
    }
    colsum[b] = run;
}

// ---------- k3: partition (LDS scan of colsum; block 0 exports boff) ----------
__global__ __launch_bounds__(256) void partition_kernel(
    const int* __restrict__ ei, const float* __restrict__ ew,
    const int* __restrict__ H, const int* __restrict__ colsum,
    uint2* __restrict__ part, int* __restrict__ boff)
{
    __shared__ int s_scan[256];
    __shared__ int s_boff[NB + 1];
    __shared__ int cur[NB];
    int t = threadIdx.x;
    int row = ((blockIdx.x & 7) << 4) | (blockIdx.x >> 3);  // XCD-aware row map
    {
        int v[SC7]; int sum = 0;
#pragma unroll
        for (int j = 0; j < SC7; ++j) {
            int idx = t * SC7 + j;
            v[j] = (idx < NB) ? colsum[idx] : 0;
            sum += v[j];
        }
        s_scan[t] = sum;
        __syncthreads();
        for (int o = 1; o < 256; o <<= 1) {
            int u = (t >= o) ? s_scan[t - o] : 0;
            __syncthreads();
            s_scan[t] += u;
            __syncthreads();
        }
        int b2 = s_scan[t] - sum;
#pragma unroll
        for (int j = 0; j < SC7; ++j) {
            int idx = t * SC7 + j;
            if (idx < NB) { s_boff[idx] = b2; b2 += v[j]; }
        }
        if (t == 0) s_boff[NB] = NE;
        __syncthreads();
    }
    if (blockIdx.x == 0)
        for (int i = t; i <= NB; i += 256) boff[i] = s_boff[i];

    for (int i = t; i < NB; i += 256)
        cur[i] = s_boff[i] + H[row * NB + i];
    __syncthreads();
    int base = row * CHUNK_E;
    int end  = min(base + CHUNK_E, NE);
    for (int e = base + t; e < end; e += 256) {
        int s = ei[e], d = ei[NE + e];
        float w = ew[e];
        int b = d >> 5;
        int pos = atomicAdd(&cur[b], 1);   // LDS atomic, block-local
        part[pos] = make_uint2((unsigned)s | ((unsigned)(d & 31) << 16),
                               __float_as_uint(w));
    }
}

// ---------- k4: fused sort + balanced edge-sweep aggregate + pool ----------
__global__ __launch_bounds__(256) void bucketagg_kernel(
    const uint2* __restrict__ ypq, const uint2* __restrict__ rootq,
    const uint2* __restrict__ part, const int* __restrict__ boff,
    const int* __restrict__ batch, float* __restrict__ pooled)
{
    __shared__ unsigned csr_lds[CAP];       // 4 KB sorted records
    __shared__ unsigned char nid[CAP];      // 1 KB node id per record
    __shared__ float accf[BK * DIM];        // 4 KB accumulators
    __shared__ int cnt[BK];                 // sort counts, then batch ids
    __shared__ int cur[BK];
    __shared__ int off[BK + 1];
    int b = blockIdx.x, t = threadIdx.x;
    int s0 = boff[b], s1 = boff[b + 1], m = s1 - s0;

    // ---- init ----
    if (t < BK) cnt[t] = 0;
#pragma unroll
    for (int i = 0; i < BK * DIM / 256; ++i) accf[t + i * 256] = 0.0f;
    __syncthreads();

    // ---- single-pass reg-staged counting sort into LDS (part read ONCE) ----
    uint2 rec[4];
    int nrec = 0;
#pragma unroll
    for (int i = 0; i < 4; ++i) {
        int idx = t + i * 256;
        if (idx < m) { rec[i] = part[s0 + idx]; nrec = i + 1; }
    }
#pragma unroll
    for (int i = 0; i < 4; ++i)
        if (i < nrec) atomicAdd(&cnt[rec[i].x >> 16], 1);
    __syncthreads();
    if (t < BK) {
        int v = cnt[t];
        int inc = v;
#pragma unroll
        for (int o = 1; o < BK; o <<= 1) {
            int u = __shfl_up(inc, o, 64);
            if (t >= o) inc += u;
        }
        off[t] = inc - v;
        cur[t] = inc - v;
        if (t == BK - 1) off[BK] = inc;
    }
    __syncthreads();
#pragma unroll
    for (int i = 0; i < 4; ++i)
        if (i < nrec) {
            uint2 pk = rec[i];
            int nl = pk.x >> 16;
            int pos = atomicAdd(&cur[nl], 1);
            csr_lds[pos] = (pk.x & 0xFFFFu) | (rne16(UIF(pk.y)) << 16);
            nid[pos] = (unsigned char)nl;
        }
    // stage batch ids into cnt (dead after sort)
    if (t < BK) {
        int n = b * BK + t;
        cnt[t] = (n < NN) ? batch[n] : -1;
    }
    __syncthreads();

    // ---- balanced edge sweep: wave w takes quarter of edges; lane (g,j) ----
    int w    = t >> 6;
    int lane = t & 63;
    int g    = lane >> 3;               // stride-8 phase
    int j    = lane & 7;                // col quad (cols 4j..4j+3)
    int per  = (m + 3) >> 2;
    int qs   = w * per;
    int qe   = min(qs + per, m);

    float v0 = 0, v1 = 0, v2 = 0, v3 = 0;
    int cur3 = -1;

#define FLUSH() { \
    atomicAdd(&accf[cur3 * DIM + 4 * j + 0], v0); \
    atomicAdd(&accf[cur3 * DIM + 4 * j + 1], v1); \
    atomicAdd(&accf[cur3 * DIM + 4 * j + 2], v2); \
    atomicAdd(&accf[cur3 * DIM + 4 * j + 3], v3); }
#define PROC(cu, ne, p) { \
    if (ne != cur3) { \
        if (cur3 >= 0) FLUSH(); \
        cur3 = ne; v0 = v1 = v2 = v3 = 0.0f; } \
    float ww = UIF((cu) & 0xFFFF0000u); \
    v0 = fmaf(ww, blo((p).x), v0); v1 = fmaf(ww, bhi((p).x), v1); \
    v2 = fmaf(ww, blo((p).y), v2); v3 = fmaf(ww, bhi((p).y), v3); }

    int e = qs + g;
    for (; e + 24 < qe; e += 32) {       // 4 edges per lane per iter
        unsigned c0 = csr_lds[e],      c1 = csr_lds[e + 8];
        unsigned c2 = csr_lds[e + 16], c3 = csr_lds[e + 24];
        int n0 = nid[e], n1 = nid[e + 8], n2 = nid[e + 16], n3 = nid[e + 24];
        uint2 p0 = ypq[(c0 & 0xFFFFu) * 8 + j];
        uint2 p1 = ypq[(c1 & 0xFFFFu) * 8 + j];
        uint2 p2 = ypq[(c2 & 0xFFFFu) * 8 + j];
        uint2 p3 = ypq[(c3 & 0xFFFFu) * 8 + j];
        PROC(c0, n0, p0); PROC(c1, n1, p1);
        PROC(c2, n2, p2); PROC(c3, n3, p3);
    }
    for (; e < qe; e += 8) {
        unsigned cu = csr_lds[e];
        int ne = nid[e];
        uint2 p = ypq[(cu & 0xFFFFu) * 8 + j];
        PROC(cu, ne, p);
    }
    if (cur3 >= 0) FLUSH();
#undef PROC
#undef FLUSH
    __syncthreads();

    // ---- root + relu in place: thread t = (node t>>3, colquad t&7) ----
    {
        int nl2 = t >> 3, j2 = t & 7;
        int n2  = b * BK + nl2;
        if (n2 < NN) {
            uint2 rr = rootq[(size_t)n2 * 8 + j2];
            float* ap = accf + nl2 * DIM + 4 * j2;
            ap[0] = fmaxf(ap[0] + blo(rr.x), 0.0f);
            ap[1] = fmaxf(ap[1] + bhi(rr.x), 0.0f);
            ap[2] = fmaxf(ap[2] + blo(rr.y), 0.0f);
            ap[3] = fmaxf(ap[3] + bhi(rr.y), 0.0f);
        }
    }
    __syncthreads();

    // ---- block combine: 8 groups x 32 cols; run-length merge over 4 nodes ----
    int gi = t >> 5, c = t & 31;
    int rung = -1; float run = 0.0f;
#pragma unroll
    for (int k = 0; k < 4; ++k) {
        int nl2 = gi * 4 + k;
        int n2  = b * BK + nl2;
        if (n2 >= NN) break;
        float v = accf[nl2 * DIM + c];
        int gg = cnt[nl2];
        if (gg != rung) {
            if (rung >= 0) atomicAdd(&pooled[rung * DIM + c], run);
            rung = gg; run = v;
        } else run += v;
    }
    if (rung >= 0) atomicAdd(&pooled[rung * DIM + c], run);
}

// ---------- k5: MLP head + log_softmax ----------
__global__ __launch_bounds__(512) void head_kernel(
    const float* __restrict__ pooled, const float* __restrict__ w_fc1,
    const float* __restrict__ b_fc1, const float* __restrict__ w_fc2,
    const float* __restrict__ b_fc2, float* __restrict__ out)
{
    __shared__ float s_fc1[DIM * DIM];
    __shared__ float s_b1[DIM];
    __shared__ float s_fc2[DIM * 2];
    __shared__ float s_b2[2];
    int tid = threadIdx.x;
    s_fc1[tid]       = w_fc1[tid];
    s_fc1[tid + 512] = w_fc1[tid + 512];
    if (tid < DIM * 2) s_fc2[tid] = w_fc2[tid];
    if (tid < DIM)     s_b1[tid]  = b_fc1[tid];
    if (tid < 2)       s_b2[tid]  = b_fc2[tid];
    __syncthreads();

    int g = tid;
    if (g >= NG) return;
    const float* p = pooled + g * DIM;
    float h2[DIM];
#pragma unroll
    for (int c = 0; c < DIM; ++c) {
        float a = s_b1[c];
#pragma unroll
        for (int k = 0; k < DIM; ++k)
            a = fmaf(p[k], s_fc1[k * DIM + c], a);
        h2[c] = a > 0.0f ? a : 0.0f;
    }
    float l0 = s_b2[0], l1 = s_b2[1];
#pragma unroll
    for (int c = 0; c < DIM; ++c) {
        l0 = fmaf(h2[c], s_fc2[c * 2 + 0], l0);
        l1 = fmaf(h2[c], s_fc2[c * 2 + 1], l1);
    }
    float m   = fmaxf(l0, l1);
    float lse = m + logf(expf(l0 - m) + expf(l1 - m));
    out[g * 2 + 0] = l0 - lse;
    out[g * 2 + 1] = l1 - lse;
}

extern "C" void kernel_launch(void* const* d_in, const int* in_sizes, int n_in,
                              void* d_out, int out_size, void* d_ws, size_t ws_size,
                              hipStream_t stream) {
    const float* x      = (const float*)d_in[0];
    const float* ew     = (const float*)d_in[1];
    const float* w_rel  = (const float*)d_in[2];
    const float* b_rel  = (const float*)d_in[3];
    const float* w_root = (const float*)d_in[4];
    const float* w_fc1  = (const float*)d_in[5];
    const float* b_fc1  = (const float*)d_in[6];
    const float* w_fc2  = (const float*)d_in[7];
    const float* b_fc2  = (const float*)d_in[8];
    const int*   ei     = (const int*)d_in[9];
    const int*   batch  = (const int*)d_in[10];
    float* out = (float*)d_out;

    char* ws = (char*)d_ws;
    unsigned* yp    = (unsigned*)ws;                           // 3.2 MB (bf16x2)
    unsigned* rootp = yp + (size_t)NN * 16;                    // 3.2 MB (bf16x2)
    uint2* part     = (uint2*)(rootp + (size_t)NN * 16);       // 6.4 MB
    int*   H        = (int*)(part + NE);                       // HB*NB = 800 KB
    int*   colsum   = H + (size_t)HB * NB;                     // NB
    int*   boff     = colsum + NB;                             // NB+1
    float* pooled   = (float*)(boff + NB + 2);                 // 64 KB

    projhist_kernel<<<PB + HB, 256, 0, stream>>>(x, w_rel, w_root, b_rel,
                                                 yp, rootp, ei, H, pooled);
    colscan<<<(NB + 255) / 256, 256, 0, stream>>>(H, colsum);
    partition_kernel<<<HB, 256, 0, stream>>>(ei, ew, H, colsum, part, boff);
    bucketagg_kernel<<<NB, 256, 0, stream>>>((const uint2*)yp, (const uint2*)rootp,
                                             part, boff, batch, pooled);
    head_kernel<<<1, 512, 0, stream>>>(pooled, w_fc1, b_fc1, w_fc2, b_fc2, out);
}

// Round 23
// 66.209 us; speedup vs baseline: 2.0120x; 2.0120x over previous
//
#include <hip/hip_runtime.h>

#define NN 50000
#define NE 800000
#define NF 128
#define DIM 32
#define NG 500
#define BK 32                         // nodes per bucket
#define NB ((NN + BK - 1) / BK)       // 1563 buckets
#define PB 782                        // proj blocks (64 rows each)
#define HB 128                        // histogram/partition blocks
#define CHUNK_E ((NE + HB - 1) / HB)  // 6250 edges per block
#define CAP 1024                      // LDS csr capacity (mean 512, +5sigma ~625)
#define SC7 7                         // scan elements per thread (256*7 >= NB+1)

typedef float  f32x4  __attribute__((ext_vector_type(4)));
typedef __bf16 bf16x8 __attribute__((ext_vector_type(8)));
typedef unsigned short u16x8 __attribute__((ext_vector_type(8)));

__device__ __forceinline__ unsigned rne16(float f) {
    unsigned u = __float_as_uint(f);
    return (u + 0x7FFFu + ((u >> 16) & 1u)) >> 16;   // bf16 round-to-nearest-even
}
#define UIF __uint_as_float
__device__ __forceinline__ float blo(unsigned p) { return UIF(p << 16); }
__device__ __forceinline__ float bhi(unsigned p) { return UIF(p & 0xFFFF0000u); }

// ---------- k1: [blocks 0..PB-1] MFMA proj ; [blocks PB..] histk + zero pooled ----------
__global__ __launch_bounds__(256) void projhist_kernel(
    const float* __restrict__ x, const float* __restrict__ w_rel,
    const float* __restrict__ w_root, const float* __restrict__ b_rel,
    unsigned* __restrict__ yp, unsigned* __restrict__ rootp,
    const int* __restrict__ ei, int* __restrict__ H, float* __restrict__ pooled)
{
    __shared__ unsigned short s_wb[64 * 136];   // 17.4 KB: W^T bf16, padded
    __shared__ float s_out[64 * 65];            // 16.6 KB: D staging, padded
    int tid = threadIdx.x;

    if (blockIdx.x >= PB) {
        // ---- histk branch (reuses s_wb as int[]); XCD-aware edge-chunk map ----
        int blk = blockIdx.x - PB;
        int row = ((blk & 7) << 4) | (blk >> 3);
        int* sh = (int*)s_wb;
        int pi = blk * 256 + tid;
        if (pi < NG * DIM) pooled[pi] = 0.0f;
        for (int i = tid; i < NB; i += 256) sh[i] = 0;
        __syncthreads();
        int base = row * CHUNK_E;
        int end  = min(base + CHUNK_E, NE);
        for (int e = base + tid; e < end; e += 256)
            atomicAdd(&sh[ei[NE + e] >> 5], 1);
        __syncthreads();
        for (int i = tid; i < NB; i += 256) H[row * NB + i] = sh[i];
        return;
    }

    // ---- stage W = [w_rel | w_root] transposed to LDS as bf16 ----
    for (int i = tid; i < 64 * NF; i += 256) {
        int k   = i >> 6;          // 0..127
        int col = i & 63;          // 0..63
        float v = (col < DIM) ? w_rel[k * DIM + col] : w_root[k * DIM + (col - DIM)];
        s_wb[col * 136 + k] = (unsigned short)rne16(v);
    }
    int rb = blockIdx.x * 64;
    __syncthreads();

    // ---- MFMA: wave w computes rows rb+w*16..+15 x 64 cols ----
    int l    = tid & 63;
    int w    = tid >> 6;
    int mrow = l & 15;
    int q    = l >> 4;                 // k-quad for A/B, row-quad for D
    int arow = min(rb + w * 16 + mrow, NN - 1);
    const float* xr = x + (size_t)arow * NF + q * 8;

    f32x4 acc0 = {0,0,0,0}, acc1 = {0,0,0,0}, acc2 = {0,0,0,0}, acc3 = {0,0,0,0};
#pragma unroll
    for (int k0 = 0; k0 < NF; k0 += 32) {
        float4 xa = *reinterpret_cast<const float4*>(xr + k0);
        float4 xb = *reinterpret_cast<const float4*>(xr + k0 + 4);
        u16x8 au;
        au[0] = (unsigned short)rne16(xa.x); au[1] = (unsigned short)rne16(xa.y);
        au[2] = (unsigned short)rne16(xa.z); au[3] = (unsigned short)rne16(xa.w);
        au[4] = (unsigned short)rne16(xb.x); au[5] = (unsigned short)rne16(xb.y);
        au[6] = (unsigned short)rne16(xb.z); au[7] = (unsigned short)rne16(xb.w);
        bf16x8 a = __builtin_bit_cast(bf16x8, au);
        int kb = k0 + q * 8;
        bf16x8 b0 = *reinterpret_cast<const bf16x8*>(&s_wb[(0  + mrow) * 136 + kb]);
        bf16x8 b1 = *reinterpret_cast<const bf16x8*>(&s_wb[(16 + mrow) * 136 + kb]);
        bf16x8 b2 = *reinterpret_cast<const bf16x8*>(&s_wb[(32 + mrow) * 136 + kb]);
        bf16x8 b3 = *reinterpret_cast<const bf16x8*>(&s_wb[(48 + mrow) * 136 + kb]);
        acc0 = __builtin_amdgcn_mfma_f32_16x16x32_bf16(a, b0, acc0, 0, 0, 0);
        acc1 = __builtin_amdgcn_mfma_f32_16x16x32_bf16(a, b1, acc1, 0, 0, 0);
        acc2 = __builtin_amdgcn_mfma_f32_16x16x32_bf16(a, b2, acc2, 0, 0, 0);
        acc3 = __builtin_amdgcn_mfma_f32_16x16x32_bf16(a, b3, acc3, 0, 0, 0);
    }
    // D layout: col = lane&15, row = (lane>>4)*4 + reg  [m89-verified]
#pragma unroll
    for (int reg = 0; reg < 4; ++reg) {
        int srow = w * 16 + q * 4 + reg;
        s_out[srow * 65 +  0 + mrow] = acc0[reg];
        s_out[srow * 65 + 16 + mrow] = acc1[reg];
        s_out[srow * 65 + 32 + mrow] = acc2[reg];
        s_out[srow * 65 + 48 + mrow] = acc3[reg];
    }
    __syncthreads();

    // ---- repack + store: cols 0..31 -> yp ; cols 32..63 + b_rel -> rootp ----
#pragma unroll
    for (int rep = 0; rep < 8; ++rep) {
        int idx = tid + rep * 256;     // 0..2047
        int row = idx >> 5;            // 0..63
        int ui  = idx & 31;            // packed-uint index
        int n   = rb + row;
        if (n < NN) {
            if (ui < 16) {
                int c0 = ui * 2;
                unsigned p = rne16(s_out[row * 65 + c0]) |
                             (rne16(s_out[row * 65 + c0 + 1]) << 16);
                yp[(size_t)n * 16 + ui] = p;
            } else {
                int c0 = (ui - 16) * 2;
                float f0 = s_out[row * 65 + DIM + c0]     + b_rel[c0];
                float f1 = s_out[row * 65 + DIM + c0 + 1] + b_rel[c0 + 1];
                rootp[(size_t)n * 16 + (ui - 16)] = rne16(f0) | (rne16(f1) << 16);
            }
        }
    }
}

// ---------- k2: column prefix over the HB block rows -> colsum ----------
__global__ __launch_bounds__(256) void colscan(
    int* __restrict__ H, int* __restrict__ colsum)
{
    int b = blockIdx.x * 256 + threadIdx.x;
    if (b >= NB) return;
    int run = 0;
#pragma unroll 8
    for (int blk = 0; blk < HB; ++blk) {
        int v = H[blk * NB + b];   // coalesced across threads
        H[blk * NB + b] = run;
        run += v;
    }
    colsum[b] = run;
}

// ---------- k3: partition (LDS scan of colsum; block 0 exports boff) ----------
__global__ __launch_bounds__(256) void partition_kernel(
    const int* __restrict__ ei, const float* __restrict__ ew,
    const int* __restrict__ H, const int* __restrict__ colsum,
    uint2* __restrict__ part, int* __restrict__ boff)
{
    __shared__ int s_scan[256];
    __shared__ int s_boff[NB + 1];
    __shared__ int cur[NB];
    int t = threadIdx.x;
    int row = ((blockIdx.x & 7) << 4) | (blockIdx.x >> 3);  // XCD-aware map
    {
        int v[SC7]; int sum = 0;
#pragma unroll
        for (int j = 0; j < SC7; ++j) {
            int idx = t * SC7 + j;
            v[j] = (idx < NB) ? colsum[idx] : 0;
            sum += v[j];
        }
        s_scan[t] = sum;
        __syncthreads();
        for (int o = 1; o < 256; o <<= 1) {
            int u = (t >= o) ? s_scan[t - o] : 0;
            __syncthreads();
            s_scan[t] += u;
            __syncthreads();
        }
        int b2 = s_scan[t] - sum;
#pragma unroll
        for (int j = 0; j < SC7; ++j) {
            int idx = t * SC7 + j;
            if (idx < NB) { s_boff[idx] = b2; b2 += v[j]; }
        }
        if (t == 0) s_boff[NB] = NE;
        __syncthreads();
    }
    if (blockIdx.x == 0)
        for (int i = t; i <= NB; i += 256) boff[i] = s_boff[i];

    for (int i = t; i < NB; i += 256)
        cur[i] = s_boff[i] + H[row * NB + i];
    __syncthreads();
    int base = row * CHUNK_E;
    int end  = min(base + CHUNK_E, NE);
    for (int e = base + t; e < end; e += 256) {
        int s = ei[e], d = ei[NE + e];
        float w = ew[e];
        int b = d >> 5;
        int pos = atomicAdd(&cur[b], 1);   // LDS atomic, block-local
        part[pos] = make_uint2((unsigned)s | ((unsigned)(d & 31) << 16),
                               __float_as_uint(w));
    }
}

// ---------- k4: fused sort (reg-staged) + 4-deep gather aggregate + pool ----------
__global__ __launch_bounds__(256) void bucketagg_kernel(
    const uint2* __restrict__ ypq, const uint2* __restrict__ rootq,
    const uint2* __restrict__ part, const int* __restrict__ boff,
    const int* __restrict__ batch, float* __restrict__ pooled)
{
    __shared__ unsigned csr_lds[CAP];   // 4 KB; overlaid by s_p[32][32] after agg
    __shared__ int cnt[BK];             // sort counts, then batch ids
    __shared__ int cur[BK];
    __shared__ int off[BK + 1];
    int b = blockIdx.x, t = threadIdx.x;
    int s0 = boff[b], s1 = boff[b + 1], m = s1 - s0;

    // ---- single-pass reg-staged counting sort into LDS (part read ONCE) ----
    uint2 rec[4];
    int nrec = 0;
    if (t < BK) cnt[t] = 0;
    __syncthreads();
#pragma unroll
    for (int i = 0; i < 4; ++i) {
        int idx = t + i * 256;
        if (idx < m) { rec[i] = part[s0 + idx]; nrec = i + 1; }
    }
#pragma unroll
    for (int i = 0; i < 4; ++i)
        if (i < nrec) atomicAdd(&cnt[rec[i].x >> 16], 1);
    __syncthreads();
    if (t < BK) {
        int v = cnt[t];
        int inc = v;
#pragma unroll
        for (int o = 1; o < BK; o <<= 1) {
            int u = __shfl_up(inc, o, 64);
            if (t >= o) inc += u;
        }
        off[t] = inc - v;
        cur[t] = inc - v;
        if (t == BK - 1) off[BK] = inc;
    }
    __syncthreads();
#pragma unroll
    for (int i = 0; i < 4; ++i)
        if (i < nrec) {
            uint2 pk = rec[i];
            int nl = pk.x >> 16;
            int pos = atomicAdd(&cur[nl], 1);
            csr_lds[pos] = (pk.x & 0xFFFFu) | (rne16(UIF(pk.y)) << 16);
        }
    // stage batch ids into cnt (dead after sort)
    if (t < BK) {
        int n = b * BK + t;
        cnt[t] = (n < NN) ? batch[n] : -1;
    }
    __syncthreads();

    // ---- agg phase: 8 lanes per node (lane j = cols 4j..4j+3), NO shfl ----
    int w    = t >> 6;                  // wave 0..3
    int lane = t & 63;
    int g    = lane >> 3;               // node group 0..7 within wave
    int j    = lane & 7;                // col quad
    int nl   = w * 8 + g;               // node 0..31
    int n    = b * BK + nl;
    float v0 = 0, v1 = 0, v2 = 0, v3 = 0;
    if (n < NN) {
        int e  = off[nl];
        int e1 = off[nl + 1];
        for (; e + 4 <= e1; e += 4) {   // 4 independent gathers in flight/lane
            unsigned c0 = csr_lds[e],     c1 = csr_lds[e + 1];
            unsigned c2 = csr_lds[e + 2], c3 = csr_lds[e + 3];
            uint2 p0 = ypq[(c0 & 0xFFFFu) * 8 + j];
            uint2 p1 = ypq[(c1 & 0xFFFFu) * 8 + j];
            uint2 p2 = ypq[(c2 & 0xFFFFu) * 8 + j];
            uint2 p3 = ypq[(c3 & 0xFFFFu) * 8 + j];
            float w0 = UIF(c0 & 0xFFFF0000u), w1 = UIF(c1 & 0xFFFF0000u);
            float w2 = UIF(c2 & 0xFFFF0000u), w3 = UIF(c3 & 0xFFFF0000u);
            v0 = fmaf(w0, blo(p0.x), v0); v1 = fmaf(w0, bhi(p0.x), v1);
            v2 = fmaf(w0, blo(p0.y), v2); v3 = fmaf(w0, bhi(p0.y), v3);
            v0 = fmaf(w1, blo(p1.x), v0); v1 = fmaf(w1, bhi(p1.x), v1);
            v2 = fmaf(w1, blo(p1.y), v2); v3 = fmaf(w1, bhi(p1.y), v3);
            v0 = fmaf(w2, blo(p2.x), v0); v1 = fmaf(w2, bhi(p2.x), v1);
            v2 = fmaf(w2, blo(p2.y), v2); v3 = fmaf(w2, bhi(p2.y), v3);
            v0 = fmaf(w3, blo(p3.x), v0); v1 = fmaf(w3, bhi(p3.x), v1);
            v2 = fmaf(w3, blo(p3.y), v2); v3 = fmaf(w3, bhi(p3.y), v3);
        }
        for (; e < e1; ++e) {
            unsigned cu = csr_lds[e];
            uint2 p = ypq[(cu & 0xFFFFu) * 8 + j];
            float ww = UIF(cu & 0xFFFF0000u);
            v0 = fmaf(ww, blo(p.x), v0); v1 = fmaf(ww, bhi(p.x), v1);
            v2 = fmaf(ww, blo(p.y), v2); v3 = fmaf(ww, bhi(p.y), v3);
        }
        uint2 rr = rootq[(size_t)n * 8 + j];
        v0 = fmaxf(v0 + blo(rr.x), 0.0f);
        v1 = fmaxf(v1 + bhi(rr.x), 0.0f);
        v2 = fmaxf(v2 + blo(rr.y), 0.0f);
        v3 = fmaxf(v3 + bhi(rr.y), 0.0f);
    }
    __syncthreads();   // all csr_lds reads done; safe to overlay

    float* s_p = (float*)csr_lds;      // [32][32] = 4 KB
    {
        float* dst = s_p + nl * DIM + 4 * j;
        dst[0] = v0; dst[1] = v1; dst[2] = v2; dst[3] = v3;
    }
    __syncthreads();

    // ---- block combine: 8 groups x 32 cols; run-length merge over 4 nodes ----
    int gi = t >> 5, c = t & 31;
    int rung = -1; float run = 0.0f;
#pragma unroll
    for (int k = 0; k < 4; ++k) {
        int nl2 = gi * 4 + k;
        int n2  = b * BK + nl2;
        if (n2 >= NN) break;
        float v = s_p[nl2 * DIM + c];
        int gg = cnt[nl2];
        if (gg != rung) {
            if (rung >= 0) atomicAdd(&pooled[rung * DIM + c], run);
            rung = gg; run = v;
        } else run += v;
    }
    if (rung >= 0) atomicAdd(&pooled[rung * DIM + c], run);
}

// ---------- k5: MLP head + log_softmax ----------
__global__ __launch_bounds__(512) void head_kernel(
    const float* __restrict__ pooled, const float* __restrict__ w_fc1,
    const float* __restrict__ b_fc1, const float* __restrict__ w_fc2,
    const float* __restrict__ b_fc2, float* __restrict__ out)
{
    __shared__ float s_fc1[DIM * DIM];
    __shared__ float s_b1[DIM];
    __shared__ float s_fc2[DIM * 2];
    __shared__ float s_b2[2];
    int tid = threadIdx.x;
    s_fc1[tid]       = w_fc1[tid];
    s_fc1[tid + 512] = w_fc1[tid + 512];
    if (tid < DIM * 2) s_fc2[tid] = w_fc2[tid];
    if (tid < DIM)     s_b1[tid]  = b_fc1[tid];
    if (tid < 2)       s_b2[tid]  = b_fc2[tid];
    __syncthreads();

    int g = tid;
    if (g >= NG) return;
    const float* p = pooled + g * DIM;
    float h2[DIM];
#pragma unroll
    for (int c = 0; c < DIM; ++c) {
        float a = s_b1[c];
#pragma unroll
        for (int k = 0; k < DIM; ++k)
            a = fmaf(p[k], s_fc1[k * DIM + c], a);
        h2[c] = a > 0.0f ? a : 0.0f;
    }
    float l0 = s_b2[0], l1 = s_b2[1];
#pragma unroll
    for (int c = 0; c < DIM; ++c) {
        l0 = fmaf(h2[c], s_fc2[c * 2 + 0], l0);
        l1 = fmaf(h2[c], s_fc2[c * 2 + 1], l1);
    }
    float m   = fmaxf(l0, l1);
    float lse = m + logf(expf(l0 - m) + expf(l1 - m));
    out[g * 2 + 0] = l0 - lse;
    out[g * 2 + 1] = l1 - lse;
}

extern "C" void kernel_launch(void* const* d_in, const int* in_sizes, int n_in,
                              void* d_out, int out_size, void* d_ws, size_t ws_size,
                              hipStream_t stream) {
    const float* x      = (const float*)d_in[0];
    const float* ew     = (const float*)d_in[1];
    const float* w_rel  = (const float*)d_in[2];
    const float* b_rel  = (const float*)d_in[3];
    const float* w_root = (const float*)d_in[4];
    const float* w_fc1  = (const float*)d_in[5];
    const float* b_fc1  = (const float*)d_in[6];
    const float* w_fc2  = (const float*)d_in[7];
    const float* b_fc2  = (const float*)d_in[8];
    const int*   ei     = (const int*)d_in[9];
    const int*   batch  = (const int*)d_in[10];
    float* out = (float*)d_out;

    char* ws = (char*)d_ws;
    unsigned* yp    = (unsigned*)ws;                           // 3.2 MB (bf16x2)
    unsigned* rootp = yp + (size_t)NN * 16;                    // 3.2 MB (bf16x2)
    uint2* part     = (uint2*)(rootp + (size_t)NN * 16);       // 6.4 MB
    int*   H        = (int*)(part + NE);                       // HB*NB = 800 KB
    int*   colsum   = H + (size_t)HB * NB;                     // NB
    int*   boff     = colsum + NB;                             // NB+1
    float* pooled   = (float*)(boff + NB + 2);                 // 64 KB

    projhist_kernel<<<PB + HB, 256, 0, stream>>>(x, w_rel, w_root, b_rel,
                                                 yp, rootp, ei, H, pooled);
    colscan<<<(NB + 255) / 256, 256, 0, stream>>>(H, colsum);
    partition_kernel<<<HB, 256, 0, stream>>>(ei, ew, H, colsum, part, boff);
    bucketagg_kernel<<<NB, 256, 0, stream>>>((const uint2*)yp, (const uint2*)rootp,
                                             part, boff, batch, pooled);
    head_kernel<<<1, 512, 0, stream>>>(pooled, w_fc1, b_fc1, w_fc2, b_fc2, out);
}